// Round 7
// baseline (97.544 us; speedup 1.0000x reference)
//
#include <hip/hip_runtime.h>

#define WINDOW 20
#define EPS 1e-8f

constexpr int B = 16;
constexpr int F = 257;
constexpr int T = 8000;
constexpr int TQ = T / 4;                           // 2000 quads per row
constexpr int CHUNK_Q = 32;                         // 128 cols per chunk
constexpr int NCH = 2;                              // chunks per block
constexpr int TILE_Q = CHUNK_Q * NCH;               // 64 quads per block
constexpr int NTILES = (TQ + TILE_Q - 1) / TILE_Q;  // 32

typedef float f32x4 __attribute__((ext_vector_type(4)));  // native vec for NT store

// LDS-only barrier: make our LDS writes visible, DON'T drain vmcnt
// (global stores / prefetched loads stay in flight across it).
__device__ __forceinline__ void bar_lds() {
  asm volatile("s_waitcnt lgkmcnt(0)" ::: "memory");
  __builtin_amdgcn_s_barrier();
}

__device__ __forceinline__ void nt_store4(float4* p, float4 v) {
  f32x4 w = {v.x, v.y, v.z, v.w};
  __builtin_nontemporal_store(w, (f32x4*)p);
}

// Fused single-read: block owns (b, 2 x 128 columns) x all 257 rows.
// 512 threads = 16 row-groups x 32 quads; each thread holds 16 rows in regs.
__global__ void __launch_bounds__(512, 6) fused_kernel(
    const float* __restrict__ mag, const float* __restrict__ bias,
    float* __restrict__ out_norm, float* __restrict__ out_mean) {

  const int b    = blockIdx.y;
  const int q0   = blockIdx.x * TILE_Q;
  const int tid  = threadIdx.x;
  const int q    = tid & (CHUNK_Q - 1);   // quad within chunk 0..31
  const int rg   = tid >> 5;              // row group 0..15
  const int wave = tid >> 6;              // 0..7
  const int lane = tid & 63;

  const float4* magq = (const float4*)(mag + (size_t)b * F * T);
  float4* outq = (float4*)(out_norm + (size_t)b * F * T);
  const float bs = bias[0];

  __shared__ float4 red[16][CHUNK_Q];      // 8 KB partial col sums
  __shared__ float  cs[20 + CHUNK_Q * 4];  // [0..19] halo, [20..147] chunk
  __shared__ float4 inv4[CHUNK_Q];

  // ---- left-halo column sums: waves 0..4, one halo quad each ----
  if (wave < 5) {
    int qh = q0 - 5 + wave;
    float4 hs = make_float4(0.f, 0.f, 0.f, 0.f);
    if (qh >= 0) {
      #pragma unroll
      for (int r = 0; r < 4; ++r) {
        float4 tv = magq[(size_t)(lane + (r << 6)) * TQ + qh];
        hs.x += tv.x; hs.y += tv.y; hs.z += tv.z; hs.w += tv.w;
      }
      if (lane == 0) {
        float4 tv = magq[(size_t)256 * TQ + qh];
        hs.x += tv.x; hs.y += tv.y; hs.z += tv.z; hs.w += tv.w;
      }
    }
    #pragma unroll
    for (int off = 32; off > 0; off >>= 1) {
      hs.x += __shfl_down(hs.x, off);
      hs.y += __shfl_down(hs.y, off);
      hs.z += __shfl_down(hs.z, off);
      hs.w += __shfl_down(hs.w, off);
    }
    if (lane == 0) {
      cs[4 * wave + 0] = hs.x;
      cs[4 * wave + 1] = hs.y;
      cs[4 * wave + 2] = hs.z;
      cs[4 * wave + 3] = hs.w;
    }
  }
  // halo LDS writes fenced by bar A of chunk 0

  for (int ch = 0; ch < NCH; ++ch) {
    const int cq0 = q0 + ch * CHUNK_Q;
    if (cq0 >= TQ) break;                 // block-uniform
    const int qc  = min(CHUNK_Q, TQ - cq0);
    const bool act = (q < qc);

    // ---- load chunk into registers + per-thread column partials ----
    float4 v[16];
    float4 v16 = make_float4(0.f, 0.f, 0.f, 0.f);
    float4 acc = make_float4(0.f, 0.f, 0.f, 0.f);
    if (act) {
      const float4* p = magq + cq0 + q;
      #pragma unroll
      for (int it = 0; it < 16; ++it) {
        float4 tv = p[(size_t)((it << 4) + rg) * TQ];
        v[it] = tv;
        acc.x += tv.x; acc.y += tv.y; acc.z += tv.z; acc.w += tv.w;
      }
      if (rg == 0) {                       // fold row f=256
        v16 = p[(size_t)256 * TQ];
        acc.x += v16.x; acc.y += v16.y; acc.z += v16.z; acc.w += v16.w;
      }
    }
    red[rg][q] = acc;
    bar_lds();                             // A

    // ---- finalize column sums (32 threads) ----
    if (tid < CHUNK_Q) {
      float4 s = make_float4(0.f, 0.f, 0.f, 0.f);
      #pragma unroll
      for (int r = 0; r < 16; ++r) {
        float4 a = red[r][tid];
        s.x += a.x; s.y += a.y; s.z += a.z; s.w += a.w;
      }
      cs[20 + 4 * tid + 0] = s.x;
      cs[20 + 4 * tid + 1] = s.y;
      cs[20 + 4 * tid + 2] = s.z;
      cs[20 + 4 * tid + 3] = s.w;
    }
    bar_lds();                             // B

    // ---- window means + inverse ----
    const int ncols = qc * 4;
    if (tid < ncols) {
      int t = cq0 * 4 + tid;
      float ws = 0.f;
      #pragma unroll
      for (int k = 0; k < WINDOW; ++k) ws += cs[20 + tid - k];
      int nwin = (t < WINDOW - 1) ? (t + 1) : WINDOW;
      float mean = ws / (float)(nwin * F) + bs;
      out_mean[b * T + t] = mean;          // fire-and-forget, never drained
      ((float*)inv4)[tid] = 1.0f / (mean + EPS);
    }
    bar_lds();                             // C

    // ---- normalize from registers + nontemporal store ----
    if (act) {
      float4 w = inv4[q];
      float4* o = outq + cq0 + q;
      #pragma unroll
      for (int it = 0; it < 16; ++it) {
        float4 tv = v[it];
        tv.x *= w.x; tv.y *= w.y; tv.z *= w.z; tv.w *= w.w;
        nt_store4(&o[(size_t)((it << 4) + rg) * TQ], tv);
      }
      if (rg == 0) {
        float4 tv = v16;
        tv.x *= w.x; tv.y *= w.y; tv.z *= w.z; tv.w *= w.w;
        nt_store4(&o[(size_t)256 * TQ], tv);
      }
    }
    // slide tail column sums into halo slot for next chunk
    if (tid < 20) cs[tid] = cs[ncols + tid];  // fenced by next bar A
  }
}

extern "C" void kernel_launch(void* const* d_in, const int* in_sizes, int n_in,
                              void* d_out, int out_size, void* d_ws, size_t ws_size,
                              hipStream_t stream) {
  const float* mag  = (const float*)d_in[0];
  const float* bias = (const float*)d_in[1];
  float* out_norm = (float*)d_out;                      // B*F*T floats
  float* out_mean = (float*)d_out + (size_t)B * F * T;  // B*T floats

  dim3 grid(NTILES, B);
  fused_kernel<<<grid, 512, 0, stream>>>(mag, bias, out_norm, out_mean);
}

// Round 8
// 49.505 us; speedup vs baseline: 1.9704x; 1.9704x over previous
//
#include <hip/hip_runtime.h>

#define WINDOW 20
#define EPS 1e-8f

constexpr int B = 16;
constexpr int F = 257;
constexpr int T = 8000;
constexpr int TQ = T / 4;                           // 2000 quads per row
constexpr int CHUNK_Q = 32;                         // 128 cols per chunk
constexpr int NCH = 2;                              // chunks per block
constexpr int TILE_Q = CHUNK_Q * NCH;               // 64 quads per block
constexpr int NTILES = (TQ + TILE_Q - 1) / TILE_Q;  // 32

typedef float f32x4 __attribute__((ext_vector_type(4)));  // native vec for NT store

// LDS-only barrier: make our LDS writes visible, DON'T drain vmcnt
// (global stores / prefetched loads stay in flight across it).
__device__ __forceinline__ void bar_lds() {
  asm volatile("s_waitcnt lgkmcnt(0)" ::: "memory");
  __builtin_amdgcn_s_barrier();
}

__device__ __forceinline__ void nt_store4(float4* p, float4 v) {
  f32x4 w = {v.x, v.y, v.z, v.w};
  __builtin_nontemporal_store(w, (f32x4*)p);
}

// Fused single-read: block owns (b, 2 x 128 columns) x all 257 rows.
// 512 threads = 16 row-groups x 32 quads; each thread holds 16 rows in regs.
// NOTE: no min-waves in launch_bounds — round 7 showed (512,6) forces
// VGPR=40 and spills the 64-VGPR register tile to scratch (2x WRITE_SIZE).
__global__ void __launch_bounds__(512) fused_kernel(
    const float* __restrict__ mag, const float* __restrict__ bias,
    float* __restrict__ out_norm, float* __restrict__ out_mean) {

  const int b    = blockIdx.y;
  const int q0   = blockIdx.x * TILE_Q;
  const int tid  = threadIdx.x;
  const int q    = tid & (CHUNK_Q - 1);   // quad within chunk 0..31
  const int rg   = tid >> 5;              // row group 0..15
  const int wave = tid >> 6;              // 0..7
  const int lane = tid & 63;

  const float4* magq = (const float4*)(mag + (size_t)b * F * T);
  float4* outq = (float4*)(out_norm + (size_t)b * F * T);
  const float bs = bias[0];

  __shared__ float4 red[16][CHUNK_Q];      // 8 KB partial col sums
  __shared__ float  cs[20 + CHUNK_Q * 4];  // [0..19] halo, [20..147] chunk
  __shared__ float4 inv4[CHUNK_Q];

  // ---- left-halo column sums: waves 0..4, one halo quad each ----
  if (wave < 5) {
    int qh = q0 - 5 + wave;
    float4 hs = make_float4(0.f, 0.f, 0.f, 0.f);
    if (qh >= 0) {
      #pragma unroll
      for (int r = 0; r < 4; ++r) {
        float4 tv = magq[(size_t)(lane + (r << 6)) * TQ + qh];
        hs.x += tv.x; hs.y += tv.y; hs.z += tv.z; hs.w += tv.w;
      }
      if (lane == 0) {
        float4 tv = magq[(size_t)256 * TQ + qh];
        hs.x += tv.x; hs.y += tv.y; hs.z += tv.z; hs.w += tv.w;
      }
    }
    #pragma unroll
    for (int off = 32; off > 0; off >>= 1) {
      hs.x += __shfl_down(hs.x, off);
      hs.y += __shfl_down(hs.y, off);
      hs.z += __shfl_down(hs.z, off);
      hs.w += __shfl_down(hs.w, off);
    }
    if (lane == 0) {
      cs[4 * wave + 0] = hs.x;
      cs[4 * wave + 1] = hs.y;
      cs[4 * wave + 2] = hs.z;
      cs[4 * wave + 3] = hs.w;
    }
  }
  // halo LDS writes fenced by bar A of chunk 0

  for (int ch = 0; ch < NCH; ++ch) {
    const int cq0 = q0 + ch * CHUNK_Q;
    if (cq0 >= TQ) break;                 // block-uniform
    const int qc  = min(CHUNK_Q, TQ - cq0);
    const bool act = (q < qc);

    // ---- load chunk into registers + per-thread column partials ----
    float4 v[16];
    float4 v16 = make_float4(0.f, 0.f, 0.f, 0.f);
    float4 acc = make_float4(0.f, 0.f, 0.f, 0.f);
    if (act) {
      const float4* p = magq + cq0 + q;
      #pragma unroll
      for (int it = 0; it < 16; ++it) {
        float4 tv = p[(size_t)((it << 4) + rg) * TQ];
        v[it] = tv;
        acc.x += tv.x; acc.y += tv.y; acc.z += tv.z; acc.w += tv.w;
      }
      if (rg == 0) {                       // fold row f=256
        v16 = p[(size_t)256 * TQ];
        acc.x += v16.x; acc.y += v16.y; acc.z += v16.z; acc.w += v16.w;
      }
    }
    red[rg][q] = acc;
    bar_lds();                             // A

    // ---- finalize column sums (32 threads) ----
    if (tid < CHUNK_Q) {
      float4 s = make_float4(0.f, 0.f, 0.f, 0.f);
      #pragma unroll
      for (int r = 0; r < 16; ++r) {
        float4 a = red[r][tid];
        s.x += a.x; s.y += a.y; s.z += a.z; s.w += a.w;
      }
      cs[20 + 4 * tid + 0] = s.x;
      cs[20 + 4 * tid + 1] = s.y;
      cs[20 + 4 * tid + 2] = s.z;
      cs[20 + 4 * tid + 3] = s.w;
    }
    bar_lds();                             // B

    // ---- window means + inverse ----
    const int ncols = qc * 4;
    if (tid < ncols) {
      int t = cq0 * 4 + tid;
      float ws = 0.f;
      #pragma unroll
      for (int k = 0; k < WINDOW; ++k) ws += cs[20 + tid - k];
      int nwin = (t < WINDOW - 1) ? (t + 1) : WINDOW;
      float mean = ws / (float)(nwin * F) + bs;
      out_mean[b * T + t] = mean;          // fire-and-forget, never drained
      ((float*)inv4)[tid] = 1.0f / (mean + EPS);
    }
    bar_lds();                             // C

    // ---- normalize from registers + nontemporal store ----
    if (act) {
      float4 w = inv4[q];
      float4* o = outq + cq0 + q;
      #pragma unroll
      for (int it = 0; it < 16; ++it) {
        float4 tv = v[it];
        tv.x *= w.x; tv.y *= w.y; tv.z *= w.z; tv.w *= w.w;
        nt_store4(&o[(size_t)((it << 4) + rg) * TQ], tv);
      }
      if (rg == 0) {
        float4 tv = v16;
        tv.x *= w.x; tv.y *= w.y; tv.z *= w.z; tv.w *= w.w;
        nt_store4(&o[(size_t)256 * TQ], tv);
      }
    }
    // slide tail column sums into halo slot for next chunk
    if (tid < 20) cs[tid] = cs[ncols + tid];  // fenced by next bar A
  }
}

extern "C" void kernel_launch(void* const* d_in, const int* in_sizes, int n_in,
                              void* d_out, int out_size, void* d_ws, size_t ws_size,
                              hipStream_t stream) {
  const float* mag  = (const float*)d_in[0];
  const float* bias = (const float*)d_in[1];
  float* out_norm = (float*)d_out;                      // B*F*T floats
  float* out_mean = (float*)d_out + (size_t)B * F * T;  // B*T floats

  dim3 grid(NTILES, B);
  fused_kernel<<<grid, 512, 0, stream>>>(mag, bias, out_norm, out_mean);
}

// Round 9
// 49.414 us; speedup vs baseline: 1.9740x; 1.0018x over previous
//
#include <hip/hip_runtime.h>

#define WINDOW 20
#define EPS 1e-8f

constexpr int B = 16;
constexpr int F = 257;
constexpr int T = 8000;
constexpr int TQ = T / 4;                             // 2000 quads per row
constexpr int CHUNK_Q = 32;                           // 128 cols per block
constexpr int NTILES = (TQ + CHUNK_Q - 1) / CHUNK_Q;  // 63

typedef float f32x4 __attribute__((ext_vector_type(4)));

// LDS-only barrier: make LDS writes visible, DON'T drain vmcnt
// (NT stores / in-flight loads stay outstanding across it).
__device__ __forceinline__ void bar_lds() {
  asm volatile("s_waitcnt lgkmcnt(0)" ::: "memory");
  __builtin_amdgcn_s_barrier();
}

__device__ __forceinline__ void nt_store4(float4* p, float4 v) {
  f32x4 w = {v.x, v.y, v.z, v.w};
  __builtin_nontemporal_store(w, (f32x4*)p);
}

// Fused single-read: block owns (b, 128 columns) x all 257 rows.
// 512 threads = 16 row-groups x 32 quads; each thread holds 16 rows in regs.
// 2 block barriers total; column-sum finalize + window means all in wave 0.
__global__ void __launch_bounds__(512) fused_kernel(
    const float* __restrict__ mag, const float* __restrict__ bias,
    float* __restrict__ out_norm, float* __restrict__ out_mean) {

  const int b    = blockIdx.y;
  const int q0   = blockIdx.x * CHUNK_Q;
  const int tid  = threadIdx.x;
  const int q    = tid & (CHUNK_Q - 1);   // quad within chunk 0..31
  const int rg   = tid >> 5;              // row group 0..15
  const int wave = tid >> 6;              // 0..7
  const int lane = tid & 63;

  const float4* magq = (const float4*)(mag + (size_t)b * F * T);
  float4* outq = (float4*)(out_norm + (size_t)b * F * T);
  const float bs = bias[0];

  __shared__ float4 red[16][CHUNK_Q];      // 8 KB partial col sums
  __shared__ float  cs[20 + CHUNK_Q * 4];  // [0..19] halo, [20..147] chunk
  __shared__ float4 inv4[CHUNK_Q];

  const int qc  = min(CHUNK_Q, TQ - q0);
  const bool act = (q < qc);

  // ---- main tile loads into registers + per-thread column partials ----
  float4 v[16];
  float4 v16 = make_float4(0.f, 0.f, 0.f, 0.f);
  float4 acc = make_float4(0.f, 0.f, 0.f, 0.f);
  if (act) {
    const float4* p = magq + q0 + q;
    #pragma unroll
    for (int it = 0; it < 16; ++it) {
      float4 tv = p[(size_t)((it << 4) + rg) * TQ];
      v[it] = tv;
      acc.x += tv.x; acc.y += tv.y; acc.z += tv.z; acc.w += tv.w;
    }
    if (rg == 0) {                         // fold row f=256
      v16 = p[(size_t)256 * TQ];
      acc.x += v16.x; acc.y += v16.y; acc.z += v16.z; acc.w += v16.w;
    }
  }

  // ---- left-halo column sums: waves 0..4, one halo quad each ----
  if (wave < 5) {
    int qh = q0 - 5 + wave;
    float4 hs = make_float4(0.f, 0.f, 0.f, 0.f);
    if (qh >= 0) {
      #pragma unroll
      for (int r = 0; r < 4; ++r) {
        float4 tv = magq[(size_t)(lane + (r << 6)) * TQ + qh];
        hs.x += tv.x; hs.y += tv.y; hs.z += tv.z; hs.w += tv.w;
      }
      if (lane == 0) {
        float4 tv = magq[(size_t)256 * TQ + qh];
        hs.x += tv.x; hs.y += tv.y; hs.z += tv.z; hs.w += tv.w;
      }
    }
    #pragma unroll
    for (int off = 32; off > 0; off >>= 1) {
      hs.x += __shfl_down(hs.x, off);
      hs.y += __shfl_down(hs.y, off);
      hs.z += __shfl_down(hs.z, off);
      hs.w += __shfl_down(hs.w, off);
    }
    if (lane == 0) {
      cs[4 * wave + 0] = hs.x;
      cs[4 * wave + 1] = hs.y;
      cs[4 * wave + 2] = hs.z;
      cs[4 * wave + 3] = hs.w;
    }
  }

  red[rg][q] = acc;
  bar_lds();                               // A

  // ---- wave 0: finalize column sums + window means + inverse ----
  if (wave == 0) {
    if (lane < CHUNK_Q) {
      float4 s = make_float4(0.f, 0.f, 0.f, 0.f);
      #pragma unroll
      for (int r = 0; r < 16; ++r) {
        float4 a = red[r][lane];
        s.x += a.x; s.y += a.y; s.z += a.z; s.w += a.w;
      }
      ((float4*)(cs + 20))[lane] = s;      // cs+20 is 16B-aligned
    }
    asm volatile("s_waitcnt lgkmcnt(0)" ::: "memory");  // wave-internal
    const int ncols = qc * 4;
    int c = lane * 2;
    if (c < ncols) {
      int t = q0 * 4 + c;
      float ws = 0.f;
      #pragma unroll
      for (int k = 0; k < WINDOW; ++k) ws += cs[20 + c - k];
      int nwin = (t < WINDOW - 1) ? (t + 1) : WINDOW;
      float mean = ws / (float)(nwin * F) + bs;
      out_mean[b * T + t] = mean;          // fire-and-forget
      ((float*)inv4)[c] = 1.0f / (mean + EPS);

      int c1 = c + 1;                      // c1 < ncols (ncols multiple of 4)
      float ws1 = ws + cs[20 + c1] - cs[c1];  // sliding update (halo zeros ok)
      int t1 = t + 1;
      int nwin1 = (t1 < WINDOW - 1) ? (t1 + 1) : WINDOW;
      float mean1 = ws1 / (float)(nwin1 * F) + bs;
      out_mean[b * T + t1] = mean1;
      ((float*)inv4)[c1] = 1.0f / (mean1 + EPS);
    }
  }
  bar_lds();                               // C

  // ---- normalize from registers + nontemporal store ----
  if (act) {
    float4 w = inv4[q];
    float4* o = outq + q0 + q;
    #pragma unroll
    for (int it = 0; it < 16; ++it) {
      float4 tv = v[it];
      tv.x *= w.x; tv.y *= w.y; tv.z *= w.z; tv.w *= w.w;
      nt_store4(&o[(size_t)((it << 4) + rg) * TQ], tv);
    }
    if (rg == 0) {
      float4 tv = v16;
      tv.x *= w.x; tv.y *= w.y; tv.z *= w.z; tv.w *= w.w;
      nt_store4(&o[(size_t)256 * TQ], tv);
    }
  }
}

extern "C" void kernel_launch(void* const* d_in, const int* in_sizes, int n_in,
                              void* d_out, int out_size, void* d_ws, size_t ws_size,
                              hipStream_t stream) {
  const float* mag  = (const float*)d_in[0];
  const float* bias = (const float*)d_in[1];
  float* out_norm = (float*)d_out;                      // B*F*T floats
  float* out_mean = (float*)d_out + (size_t)B * F * T;  // B*T floats

  dim3 grid(NTILES, B);
  fused_kernel<<<grid, 512, 0, stream>>>(mag, bias, out_norm, out_mean);
}

// Round 10
// 45.536 us; speedup vs baseline: 2.1421x; 1.0852x over previous
//
#include <hip/hip_runtime.h>

#define WINDOW 20
#define EPS 1e-8f

constexpr int B = 16;
constexpr int F = 257;
constexpr int T = 8000;
constexpr int TQ = T / 4;                             // 2000 quads per row
constexpr int CHUNK_Q = 32;                           // 128 cols per block
constexpr int NTILES = (TQ + CHUNK_Q - 1) / CHUNK_Q;  // 63
constexpr int NBLK = NTILES * B;                      // 1008 = 8 * 126
constexpr int NXCD = 8;
constexpr int PER_XCD = NBLK / NXCD;                  // 126 (exact)

typedef float f32x4 __attribute__((ext_vector_type(4)));

// LDS-only barrier: make LDS writes visible, DON'T drain vmcnt
// (NT stores / in-flight loads stay outstanding across it).
__device__ __forceinline__ void bar_lds() {
  asm volatile("s_waitcnt lgkmcnt(0)" ::: "memory");
  __builtin_amdgcn_s_barrier();
}

__device__ __forceinline__ void nt_store4(float4* p, float4 v) {
  f32x4 w = {v.x, v.y, v.z, v.w};
  __builtin_nontemporal_store(w, (f32x4*)p);
}

// Fused single-read: block owns (b, 128 columns) x all 257 rows.
// 512 threads = 16 row-groups x 32 quads; each thread holds 16 rows in regs.
// 1D grid + chunked XCD swizzle: consecutive tiles of the same b land on the
// same XCD so halo re-reads hit the XCD-local L2.
__global__ void __launch_bounds__(512) fused_kernel(
    const float* __restrict__ mag, const float* __restrict__ bias,
    float* __restrict__ out_norm, float* __restrict__ out_mean) {

  // ---- chunked XCD swizzle (bijective: NBLK % 8 == 0) ----
  const int id   = blockIdx.x;
  const int xcd  = id & (NXCD - 1);       // default dispatch: id%8 -> XCD
  const int slot = id >> 3;               // 0..125
  const int gidx = xcd * PER_XCD + slot;  // contiguous run per XCD
  const int bx   = gidx % NTILES;         // tile index (consecutive per XCD)
  const int b    = gidx / NTILES;

  const int q0   = bx * CHUNK_Q;
  const int tid  = threadIdx.x;
  const int q    = tid & (CHUNK_Q - 1);   // quad within chunk 0..31
  const int rg   = tid >> 5;              // row group 0..15
  const int wave = tid >> 6;              // 0..7
  const int lane = tid & 63;

  const float4* magq = (const float4*)(mag + (size_t)b * F * T);
  float4* outq = (float4*)(out_norm + (size_t)b * F * T);
  const float bs = bias[0];

  __shared__ float4 red[16][CHUNK_Q];      // 8 KB partial col sums
  __shared__ float  cs[20 + CHUNK_Q * 4];  // [0..19] halo, [20..147] chunk
  __shared__ float4 inv4[CHUNK_Q];

  const int qc  = min(CHUNK_Q, TQ - q0);
  const bool act = (q < qc);

  // ---- left-halo loads FIRST (latency hides under main tile loads) ----
  float4 h0, h1, h2, h3, h4;
  int qh = q0 - 5 + wave;
  const bool do_halo = (wave < 5) && (qh >= 0);
  if (do_halo) {
    const float4* ph = magq + qh;
    h0 = ph[(size_t)(lane +   0) * TQ];
    h1 = ph[(size_t)(lane +  64) * TQ];
    h2 = ph[(size_t)(lane + 128) * TQ];
    h3 = ph[(size_t)(lane + 192) * TQ];
    h4 = (lane == 0) ? ph[(size_t)256 * TQ] : make_float4(0.f, 0.f, 0.f, 0.f);
  }

  // ---- main tile loads into registers + per-thread column partials ----
  float4 v[16];
  float4 v16 = make_float4(0.f, 0.f, 0.f, 0.f);
  float4 acc = make_float4(0.f, 0.f, 0.f, 0.f);
  if (act) {
    const float4* p = magq + q0 + q;
    #pragma unroll
    for (int it = 0; it < 16; ++it) {
      float4 tv = p[(size_t)((it << 4) + rg) * TQ];
      v[it] = tv;
      acc.x += tv.x; acc.y += tv.y; acc.z += tv.z; acc.w += tv.w;
    }
    if (rg == 0) {                         // fold row f=256
      v16 = p[(size_t)256 * TQ];
      acc.x += v16.x; acc.y += v16.y; acc.z += v16.z; acc.w += v16.w;
    }
  }

  // ---- halo reduce (data already in flight) ----
  if (wave < 5) {
    float4 hs = make_float4(0.f, 0.f, 0.f, 0.f);
    if (do_halo) {
      hs.x = ((h0.x + h1.x) + (h2.x + h3.x)) + h4.x;
      hs.y = ((h0.y + h1.y) + (h2.y + h3.y)) + h4.y;
      hs.z = ((h0.z + h1.z) + (h2.z + h3.z)) + h4.z;
      hs.w = ((h0.w + h1.w) + (h2.w + h3.w)) + h4.w;
    }
    #pragma unroll
    for (int off = 32; off > 0; off >>= 1) {
      hs.x += __shfl_down(hs.x, off);
      hs.y += __shfl_down(hs.y, off);
      hs.z += __shfl_down(hs.z, off);
      hs.w += __shfl_down(hs.w, off);
    }
    if (lane == 0) {
      cs[4 * wave + 0] = hs.x;
      cs[4 * wave + 1] = hs.y;
      cs[4 * wave + 2] = hs.z;
      cs[4 * wave + 3] = hs.w;
    }
  }

  red[rg][q] = acc;
  bar_lds();                               // A

  // ---- wave 0: finalize column sums + window means + inverse ----
  if (wave == 0) {
    if (lane < CHUNK_Q) {
      float4 s = make_float4(0.f, 0.f, 0.f, 0.f);
      #pragma unroll
      for (int r = 0; r < 16; ++r) {
        float4 a = red[r][lane];
        s.x += a.x; s.y += a.y; s.z += a.z; s.w += a.w;
      }
      ((float4*)(cs + 20))[lane] = s;      // cs+20 is 16B-aligned
    }
    asm volatile("s_waitcnt lgkmcnt(0)" ::: "memory");  // wave-internal
    const int ncols = qc * 4;
    int c = lane * 2;
    if (c < ncols) {
      int t = q0 * 4 + c;
      float ws = 0.f;
      #pragma unroll
      for (int k = 0; k < WINDOW; ++k) ws += cs[20 + c - k];
      int nwin = (t < WINDOW - 1) ? (t + 1) : WINDOW;
      float mean = ws / (float)(nwin * F) + bs;
      out_mean[b * T + t] = mean;          // fire-and-forget
      ((float*)inv4)[c] = 1.0f / (mean + EPS);

      int c1 = c + 1;                      // c1 < ncols (ncols multiple of 4)
      float ws1 = ws + cs[20 + c1] - cs[c1];  // sliding update
      int t1 = t + 1;
      int nwin1 = (t1 < WINDOW - 1) ? (t1 + 1) : WINDOW;
      float mean1 = ws1 / (float)(nwin1 * F) + bs;
      out_mean[b * T + t1] = mean1;
      ((float*)inv4)[c1] = 1.0f / (mean1 + EPS);
    }
  }
  bar_lds();                               // C

  // ---- normalize from registers + nontemporal store ----
  if (act) {
    float4 w = inv4[q];
    float4* o = outq + q0 + q;
    #pragma unroll
    for (int it = 0; it < 16; ++it) {
      float4 tv = v[it];
      tv.x *= w.x; tv.y *= w.y; tv.z *= w.z; tv.w *= w.w;
      nt_store4(&o[(size_t)((it << 4) + rg) * TQ], tv);
    }
    if (rg == 0) {
      float4 tv = v16;
      tv.x *= w.x; tv.y *= w.y; tv.z *= w.z; tv.w *= w.w;
      nt_store4(&o[(size_t)256 * TQ], tv);
    }
  }
}

extern "C" void kernel_launch(void* const* d_in, const int* in_sizes, int n_in,
                              void* d_out, int out_size, void* d_ws, size_t ws_size,
                              hipStream_t stream) {
  const float* mag  = (const float*)d_in[0];
  const float* bias = (const float*)d_in[1];
  float* out_norm = (float*)d_out;                      // B*F*T floats
  float* out_mean = (float*)d_out + (size_t)B * F * T;  // B*T floats

  fused_kernel<<<NBLK, 512, 0, stream>>>(mag, bias, out_norm, out_mean);
}